// Round 9
// baseline (5309.252 us; speedup 1.0000x reference)
//
#include <hip/hip_runtime.h>

// Problem constants
#define TSTEPS 1024
#define HDIM   1024
#define INDIM  512
#define NGATE  4096     // 4*HDIM

// Fused-scan grid: 192 WGs x 1024 threads (proven-launchable coop envelope).
// L1 (wg<64): 16 units/WG, wave q owns unit u0+q, all 4 gates.
// L23: 8 units/WG, wave q owns unit u0+(q>>1), gate pair q&1, serving BOTH
//      layer 2 and layer 3 (shared weights).
#define NWG_L1  64
#define NWG_L23 128
#define NWG_TOT 192
#define POISON  0xAAAAAAAAu
#define SPIN_MAX (1 << 20)   // deadlock valve: fail loud, never hang

// ---------------------------------------------------------------------------
// R8 post-mortem: VGPR_Count=64 and dur unchanged -> compiler STILL reloads
// the 64 weight floats per t-iteration (48 MB/step across the grid ~ 4us at
// LLC bandwidth; matches the 90% non-VALU time). Memory-clobber asm doesn't
// tie VALUES to registers. Fix: "+v" operand constraints on every weight
// component, executed INSIDE the loop — the value becomes opaque and must
// stay VGPR-resident; remat from memory is impossible. launch_bounds(1024,4)
// allows 512 VGPR/thread, so allocation is legal. Verify: VGPR_Count >= 130.
// ---------------------------------------------------------------------------
#define PIN2(v) asm volatile("" : "+v"((v).x), "+v"((v).y))

__device__ __forceinline__ float agent_loadf(const float* p) {
    return __hip_atomic_load(const_cast<float*>(p), __ATOMIC_RELAXED,
                             __HIP_MEMORY_SCOPE_AGENT);
}
__device__ __forceinline__ void agent_storef(float* p, float v) {
    __hip_atomic_store(p, v, __ATOMIC_RELAXED, __HIP_MEMORY_SCOPE_AGENT);
}
// Wave-cooperative poll: each lane owns one dword; loop until no lane's
// dword is the poison pattern. The poll IS the data load.
__device__ __forceinline__ float poll_row(const float* p) {
    float v = 0.f;
    for (int it = 0; it < SPIN_MAX; ++it) {
        v = agent_loadf(p);
        if (__ballot(__float_as_uint(v) == POISON) == 0ULL) break;
        __builtin_amdgcn_s_sleep(1);
    }
    return v;
}
__device__ __forceinline__ float wave_sum64(float v) {
#pragma unroll
    for (int d = 1; d < 64; d <<= 1) v += __shfl_xor(v, d, 64);
    return v;
}
__device__ __forceinline__ float sigm(float x) { return 1.f / (1.f + __expf(-x)); }

// ---------------------------------------------------------------------------
// GEMM for layer-1 input gates: G[t][n] = concat(x,time)[t] . Wih1[n] + b.
// ---------------------------------------------------------------------------
#define BM 64
#define BN 64
#define BK 32

__global__ __launch_bounds__(256) void gemm_tn(
    const float* __restrict__ B,
    const float* __restrict__ bias1,
    const float* __restrict__ bias2,
    float* __restrict__ C,
    int M, int N, int K,
    const float* __restrict__ x,
    const float* __restrict__ timev)
{
    __shared__ float As[BK][BM + 4];
    __shared__ float Bs[BK][BN + 4];

    const int tid = threadIdx.x;
    const int mblocks = M / BM;
    const int bm = blockIdx.x % mblocks;
    const int bn = blockIdx.x / mblocks;
    const int t0 = bm * BM;
    const int n0 = bn * BN;

    const int tx = tid & 15;
    const int ty = tid >> 4;

    float acc[4][4] = {{0.f}};

    for (int kc = 0; kc < K; kc += BK) {
#pragma unroll
        for (int i = 0; i < 8; i++) {
            int idx = tid + i * 256;
            int r = idx >> 5;
            int c = idx & 31;
            int col = kc + c;
            int trow = t0 + r;
            float av = (col < INDIM) ? x[(size_t)trow * INDIM + col]
                                     : ((col == INDIM) ? timev[trow] : 0.f);
            As[c][r] = av;
            int nrow = n0 + r;
            Bs[c][r] = (col < K) ? B[(size_t)nrow * K + col] : 0.f;
        }
        __syncthreads();

#pragma unroll
        for (int kk = 0; kk < BK; kk++) {
            float a[4], b[4];
#pragma unroll
            for (int i = 0; i < 4; i++) a[i] = As[kk][ty * 4 + i];
#pragma unroll
            for (int j = 0; j < 4; j++) b[j] = Bs[kk][tx * 4 + j];
#pragma unroll
            for (int i = 0; i < 4; i++)
#pragma unroll
                for (int j = 0; j < 4; j++)
                    acc[i][j] = fmaf(a[i], b[j], acc[i][j]);
        }
        __syncthreads();
    }

#pragma unroll
    for (int i = 0; i < 4; i++) {
        int trow = t0 + ty * 4 + i;
#pragma unroll
        for (int j = 0; j < 4; j++) {
            int n = n0 + tx * 4 + j;
            C[(size_t)trow * N + n] = acc[i][j] + bias1[n] + bias2[n];
        }
    }
}

// ---------------------------------------------------------------------------
// Fused dataflow 3-layer scan. No barriers, no flags: consumers poll the
// poisoned H rows directly. Weights pinned VGPR-resident via PIN2.
// ---------------------------------------------------------------------------
__global__ __launch_bounds__(1024, 4) void fused_scan(
    const float* Whh1,
    const float* G1,
    const float* Wih2,
    const float* Whh2,
    const float* bih2,
    const float* bhh2,
    const float* h0_1, const float* c0_1,
    const float* h0_2, const float* c0_2,
    const float* h0_3, const float* c0_3,
    float* H1, float* H2, float* H3)
{
    __shared__ float hs1[HDIM];
    __shared__ float hs2[HDIM];
    __shared__ float hs3[HDIM];
    __shared__ float gbuf[16][4];  // L1: [unit 0..15][gate]; L23: 0-7 L2, 8-15 L3

    const int tid = threadIdx.x;
    const int wg  = blockIdx.x;
    const int q   = tid >> 6;      // wave 0..15
    const int s   = tid & 63;

    if (wg < NWG_L1) {
        // ------- Layer 1: WG owns 16 units, wave q owns unit u0+q -------
        const int u0 = wg << 4;
        const int u  = u0 + q;
        float2 w[4][8];
#pragma unroll
        for (int g = 0; g < 4; ++g) {
            const float* row = Whh1 + (size_t)((g << 10) + u) * HDIM + 2 * s;
#pragma unroll
            for (int m = 0; m < 8; ++m)
                w[g][m] = *(const float2*)(row + 128 * m);
        }
        float c1 = (tid < 16) ? c0_1[u0 + tid] : 0.f;

        for (int t = 0; t < TSTEPS; ++t) {
            // pin weights live in VGPRs every iteration (zero instructions)
#pragma unroll
            for (int g = 0; g < 4; ++g)
#pragma unroll
                for (int m = 0; m < 8; ++m) PIN2(w[g][m]);

            float Gv0 = 0.f, Gv1 = 0.f, Gv2 = 0.f, Gv3 = 0.f;
            if (tid < 16) {   // prefetch gate inputs (normal cached loads)
                const float* gptr = G1 + (size_t)t * NGATE + u0 + tid;
                Gv0 = gptr[0];
                Gv1 = gptr[1024];
                Gv2 = gptr[2048];
                Gv3 = gptr[3072];
            }
            // stage h1[t-1]: poll the data itself
            hs1[tid] = (t == 0) ? h0_1[tid]
                               : poll_row(H1 + (size_t)(t - 1) * HDIM + tid);
            __syncthreads();                                   // A: staged

            float2 a0 = make_float2(0.f, 0.f), a1 = a0, a2 = a0, a3 = a0;
#pragma unroll
            for (int m = 0; m < 8; ++m) {
                float2 hv = *(const float2*)&hs1[2 * s + 128 * m];
                a0.x = fmaf(w[0][m].x, hv.x, a0.x);
                a0.y = fmaf(w[0][m].y, hv.y, a0.y);
                a1.x = fmaf(w[1][m].x, hv.x, a1.x);
                a1.y = fmaf(w[1][m].y, hv.y, a1.y);
                a2.x = fmaf(w[2][m].x, hv.x, a2.x);
                a2.y = fmaf(w[2][m].y, hv.y, a2.y);
                a3.x = fmaf(w[3][m].x, hv.x, a3.x);
                a3.y = fmaf(w[3][m].y, hv.y, a3.y);
            }
            float s0 = wave_sum64(a0.x + a0.y);
            float s1 = wave_sum64(a1.x + a1.y);
            float s2 = wave_sum64(a2.x + a2.y);
            float s3 = wave_sum64(a3.x + a3.y);
            if (s == 0) {
                gbuf[q][0] = s0;
                gbuf[q][1] = s1;
                gbuf[q][2] = s2;
                gbuf[q][3] = s3;
            }
            __syncthreads();                                   // B: sums ready

            if (tid < 16) {
                float gi = gbuf[tid][0] + Gv0;
                float gf = gbuf[tid][1] + Gv1;
                float gg = gbuf[tid][2] + Gv2;
                float go = gbuf[tid][3] + Gv3;
                float i_ = sigm(gi), f_ = sigm(gf), g_ = tanhf(gg), o_ = sigm(go);
                c1 = f_ * c1 + i_ * g_;
                float hn = o_ * tanhf(c1);
                agent_storef(H1 + (size_t)t * HDIM + u0 + tid, hn);
            }
            // no drain, no flag: the stored dwords ARE the signal
        }
    } else {
        // ---- Layers 2 & 3 (shared weights): WG owns 8 units ----
        const int ul = q >> 1;     // unit-local 0..7
        const int gp = q & 1;      // 0 -> gates (i,f), 1 -> gates (g,o)
        const int u0 = (wg - NWG_L1) << 3;
        const int u  = u0 + ul;
        float2 wi[2][8], wh[2][8];
#pragma unroll
        for (int j = 0; j < 2; ++j) {
            const float* ri = Wih2 + (size_t)(((2 * gp + j) << 10) + u) * HDIM + 2 * s;
            const float* rh = Whh2 + (size_t)(((2 * gp + j) << 10) + u) * HDIM + 2 * s;
#pragma unroll
            for (int m = 0; m < 8; ++m) {
                wi[j][m] = *(const float2*)(ri + 128 * m);
                wh[j][m] = *(const float2*)(rh + 128 * m);
            }
        }
        float bias0 = 0.f, bias1v = 0.f, bias2v = 0.f, bias3 = 0.f, cst = 0.f;
        if (tid < 16) {
            int uu = u0 + (tid & 7);
            bias0  = bih2[uu]        + bhh2[uu];
            bias1v = bih2[1024 + uu] + bhh2[1024 + uu];
            bias2v = bih2[2048 + uu] + bhh2[2048 + uu];
            bias3  = bih2[3072 + uu] + bhh2[3072 + uu];
            cst = (tid < 8) ? c0_2[u0 + tid] : c0_3[u0 + tid - 8];
        }

        // iteration t: layer2 tick t (needs h1[t], h2[t-1]) and
        //              layer3 tick t-1 (needs h2[t-1], h3[t-2])
        for (int t = 0; t <= TSTEPS; ++t) {
            // pin weights live in VGPRs every iteration (zero instructions)
#pragma unroll
            for (int j = 0; j < 2; ++j)
#pragma unroll
                for (int m = 0; m < 8; ++m) { PIN2(wi[j][m]); PIN2(wh[j][m]); }

            const bool do2 = (t < TSTEPS);
            const bool do3 = (t >= 1);

            if (do2)
                hs1[tid] = poll_row(H1 + (size_t)t * HDIM + tid);
            hs2[tid] = (t == 0) ? h0_2[tid]
                                : poll_row(H2 + (size_t)(t - 1) * HDIM + tid);
            if (do3)
                hs3[tid] = (t == 1) ? h0_3[tid]
                                    : poll_row(H3 + (size_t)(t - 2) * HDIM + tid);
            __syncthreads();                                   // A: staged

            // unconditional dots; inactive-edge garbage discarded at update
            float2 p20 = make_float2(0.f, 0.f), p21 = p20, p30 = p20, p31 = p20;
#pragma unroll
            for (int m = 0; m < 8; ++m) {
                float2 h1v = *(const float2*)&hs1[2 * s + 128 * m];
                float2 h2v = *(const float2*)&hs2[2 * s + 128 * m];
                float2 h3v = *(const float2*)&hs3[2 * s + 128 * m];
                p20.x = fmaf(wi[0][m].x, h1v.x, p20.x);
                p20.y = fmaf(wi[0][m].y, h1v.y, p20.y);
                p21.x = fmaf(wi[1][m].x, h1v.x, p21.x);
                p21.y = fmaf(wi[1][m].y, h1v.y, p21.y);
                p20.x = fmaf(wh[0][m].x, h2v.x, p20.x);
                p20.y = fmaf(wh[0][m].y, h2v.y, p20.y);
                p21.x = fmaf(wh[1][m].x, h2v.x, p21.x);
                p21.y = fmaf(wh[1][m].y, h2v.y, p21.y);
                p30.x = fmaf(wi[0][m].x, h2v.x, p30.x);
                p30.y = fmaf(wi[0][m].y, h2v.y, p30.y);
                p31.x = fmaf(wi[1][m].x, h2v.x, p31.x);
                p31.y = fmaf(wi[1][m].y, h2v.y, p31.y);
                p30.x = fmaf(wh[0][m].x, h3v.x, p30.x);
                p30.y = fmaf(wh[0][m].y, h3v.y, p30.y);
                p31.x = fmaf(wh[1][m].x, h3v.x, p31.x);
                p31.y = fmaf(wh[1][m].y, h3v.y, p31.y);
            }
            float s20 = wave_sum64(p20.x + p20.y);
            float s21 = wave_sum64(p21.x + p21.y);
            float s30 = wave_sum64(p30.x + p30.y);
            float s31 = wave_sum64(p31.x + p31.y);
            if (s == 0) {
                gbuf[ul][2 * gp]          = s20;
                gbuf[ul][2 * gp + 1]      = s21;
                gbuf[8 + ul][2 * gp]      = s30;
                gbuf[8 + ul][2 * gp + 1]  = s31;
            }
            __syncthreads();                                   // B: sums ready

            if (tid < 16) {
                const bool act = (tid < 8) ? do2 : do3;
                if (act) {
                    float gi = gbuf[tid][0] + bias0;
                    float gf = gbuf[tid][1] + bias1v;
                    float gg = gbuf[tid][2] + bias2v;
                    float go = gbuf[tid][3] + bias3;
                    float i_ = sigm(gi), f_ = sigm(gf), g_ = tanhf(gg), o_ = sigm(go);
                    cst = f_ * cst + i_ * g_;
                    float hn = o_ * tanhf(cst);
                    float* dst = (tid < 8)
                        ? (H2 + (size_t)t * HDIM + u0 + tid)
                        : (H3 + (size_t)(t - 1) * HDIM + u0 + (tid - 8));
                    agent_storef(dst, hn);
                }
            }
        }
    }
}

// ---------------------------------------------------------------------------
// Attention
// ---------------------------------------------------------------------------
__global__ __launch_bounds__(256) void attn_dot(
    const float* __restrict__ H3, float* __restrict__ attn)
{
    const int t = blockIdx.x * 4 + (threadIdx.x >> 6);
    const int lane = threadIdx.x & 63;
    const float* hrow = H3 + (size_t)t * HDIM;
    const float* hf = H3 + (size_t)(TSTEPS - 1) * HDIM;
    float p = 0.f;
    for (int j = lane; j < HDIM; j += 64) p = fmaf(hrow[j], hf[j], p);
#pragma unroll
    for (int d = 32; d; d >>= 1) p += __shfl_down(p, d, 64);
    if (lane == 0) attn[t] = p;
}

__global__ __launch_bounds__(64) void softmax_1024(float* attn)
{
    const int lane = threadIdx.x;
    float vals[16];
    float m = -1e30f;
#pragma unroll
    for (int i = 0; i < 16; i++) {
        vals[i] = attn[lane + i * 64];
        m = fmaxf(m, vals[i]);
    }
#pragma unroll
    for (int d = 32; d; d >>= 1) m = fmaxf(m, __shfl_xor(m, d, 64));
    float s = 0.f;
#pragma unroll
    for (int i = 0; i < 16; i++) {
        vals[i] = expf(vals[i] - m);
        s += vals[i];
    }
#pragma unroll
    for (int d = 32; d; d >>= 1) s += __shfl_xor(s, d, 64);
    float inv = 1.f / s;
#pragma unroll
    for (int i = 0; i < 16; i++) attn[lane + i * 64] = vals[i] * inv;
}

__global__ __launch_bounds__(256) void context_kernel(
    const float* __restrict__ H3, const float* __restrict__ w,
    float* __restrict__ out)
{
    const int u = blockIdx.x * 4 + (threadIdx.x >> 6);
    const int lane = threadIdx.x & 63;
    float p = 0.f;
    for (int t = lane; t < TSTEPS; t += 64)
        p = fmaf(H3[(size_t)t * HDIM + u], w[t], p);
#pragma unroll
    for (int d = 32; d; d >>= 1) p += __shfl_down(p, d, 64);
    if (lane == 0) out[u] = p;
}

// ---------------------------------------------------------------------------
// Launch
// ---------------------------------------------------------------------------
extern "C" void kernel_launch(void* const* d_in, const int* in_sizes, int n_in,
                              void* d_out, int out_size, void* d_ws, size_t ws_size,
                              hipStream_t stream)
{
    const float* x     = (const float*)d_in[0];
    const float* timev = (const float*)d_in[1];
    const float* h0_1  = (const float*)d_in[2];
    const float* c0_1  = (const float*)d_in[3];
    const float* h0_2  = (const float*)d_in[4];
    const float* c0_2  = (const float*)d_in[5];
    const float* h0_3  = (const float*)d_in[6];
    const float* c0_3  = (const float*)d_in[7];
    const float* Wih1  = (const float*)d_in[8];
    const float* Whh1  = (const float*)d_in[9];
    const float* bih1  = (const float*)d_in[10];
    const float* bhh1  = (const float*)d_in[11];
    const float* Wih2  = (const float*)d_in[12];
    const float* Whh2  = (const float*)d_in[13];
    const float* bih2  = (const float*)d_in[14];
    const float* bhh2  = (const float*)d_in[15];

    float* ws   = (float*)d_ws;
    float* G    = ws;                          // 1024*4096
    float* H1   = G + (size_t)TSTEPS * NGATE;
    float* H2   = H1 + (size_t)TSTEPS * HDIM;
    float* H3   = H2 + (size_t)TSTEPS * HDIM;
    float* attn = H3 + (size_t)TSTEPS * HDIM;
    float* out  = (float*)d_out;

    // Poison H1..H3 (contiguous): the data-poll protocol depends on it.
    hipMemsetAsync(H1, 0xAA, (size_t)3 * TSTEPS * HDIM * sizeof(float), stream);

    // Layer-1 input gates: G = concat(x,time) @ Wih1^T + bih1 + bhh1
    gemm_tn<<<dim3(1024), dim3(256), 0, stream>>>(Wih1, bih1, bhh1, G,
                                                  TSTEPS, NGATE, INDIM + 1, x, timev);

    {
        const float* a0 = Whh1;  const float* a1 = G;
        const float* a2 = Wih2;  const float* a3 = Whh2;
        const float* a4 = bih2;  const float* a5 = bhh2;
        const float* a6 = h0_1;  const float* a7 = c0_1;
        const float* a8 = h0_2;  const float* a9 = c0_2;
        const float* a10 = h0_3; const float* a11 = c0_3;
        float* a12 = H1; float* a13 = H2; float* a14 = H3;
        void* args[] = {&a0,&a1,&a2,&a3,&a4,&a5,&a6,&a7,&a8,&a9,&a10,&a11,
                        &a12,&a13,&a14};
        hipLaunchCooperativeKernel((void*)fused_scan, dim3(NWG_TOT), dim3(1024),
                                   args, 0, stream);
    }

    // Attention
    attn_dot<<<dim3(256), dim3(256), 0, stream>>>(H3, attn);
    softmax_1024<<<dim3(1), dim3(64), 0, stream>>>(attn);
    context_kernel<<<dim3(256), dim3(256), 0, stream>>>(H3, attn, out);
}

// Round 10
// 5300.774 us; speedup vs baseline: 1.0016x; 1.0016x over previous
//
#include <hip/hip_runtime.h>

// Problem constants
#define TSTEPS 1024
#define HDIM   1024
#define INDIM  512
#define NGATE  4096     // 4*HDIM

// Fused-scan grid: 192 WGs x 1024 threads (proven-launchable coop envelope).
// L1 (wg<64): 16 units/WG, wave q owns unit u0+q, all 4 gates (64 w-floats).
// L23: 8 units/WG, wave q owns unit u0+(q>>1), gate pair q&1 (64 w-floats),
//      serving BOTH layer 2 and layer 3 (shared weights).
#define NWG_L1  64
#define NWG_L23 128
#define NWG_TOT 192
#define POISON  0xAAAAAAAAu
#define SPIN_MAX (1 << 20)   // deadlock valve: fail loud, never hang

// ---------------------------------------------------------------------------
// R9 post-mortem: PIN2 + 64-VGPR budget -> allocator satisfied pins by
// SPILLING to scratch (WRITE_SIZE 18.4->22.5 MB, VALUBusy 15.5%, dur +10%).
// Root cause across r7-r9: the allocator targets 8 waves/EU occupancy ->
// 64-VGPR cap -> weights cannot be resident -> remat (r7/r8, ~48 MB/step
// LLC refetch ~ 4us/step) or spill (r9). launch_bounds only sets the MIN
// waves/EU. Fix: amdgpu_waves_per_eu(4,4) pins occupancy at exactly our one
// 1024-thread block/CU -> full 128-VGPR budget -> PIN2 forces residency
// within it. Verify: VGPR_Count ~110-128 AND WRITE_SIZE back to ~18.4 MB.
// ---------------------------------------------------------------------------
#define PIN2(v) asm volatile("" : "+v"((v).x), "+v"((v).y))

__device__ __forceinline__ float agent_loadf(const float* p) {
    return __hip_atomic_load(const_cast<float*>(p), __ATOMIC_RELAXED,
                             __HIP_MEMORY_SCOPE_AGENT);
}
__device__ __forceinline__ void agent_storef(float* p, float v) {
    __hip_atomic_store(p, v, __ATOMIC_RELAXED, __HIP_MEMORY_SCOPE_AGENT);
}
// Wave-cooperative poll: each lane owns one dword; loop until no lane's
// dword is the poison pattern. The poll IS the data load.
__device__ __forceinline__ float poll_row(const float* p) {
    float v = 0.f;
    for (int it = 0; it < SPIN_MAX; ++it) {
        v = agent_loadf(p);
        if (__ballot(__float_as_uint(v) == POISON) == 0ULL) break;
        __builtin_amdgcn_s_sleep(1);
    }
    return v;
}
__device__ __forceinline__ float wave_sum64(float v) {
#pragma unroll
    for (int d = 1; d < 64; d <<= 1) v += __shfl_xor(v, d, 64);
    return v;
}
__device__ __forceinline__ float sigm(float x) { return 1.f / (1.f + __expf(-x)); }

// ---------------------------------------------------------------------------
// GEMM for layer-1 input gates: G[t][n] = concat(x,time)[t] . Wih1[n] + b.
// ---------------------------------------------------------------------------
#define BM 64
#define BN 64
#define BK 32

__global__ __launch_bounds__(256) void gemm_tn(
    const float* __restrict__ B,
    const float* __restrict__ bias1,
    const float* __restrict__ bias2,
    float* __restrict__ C,
    int M, int N, int K,
    const float* __restrict__ x,
    const float* __restrict__ timev)
{
    __shared__ float As[BK][BM + 4];
    __shared__ float Bs[BK][BN + 4];

    const int tid = threadIdx.x;
    const int mblocks = M / BM;
    const int bm = blockIdx.x % mblocks;
    const int bn = blockIdx.x / mblocks;
    const int t0 = bm * BM;
    const int n0 = bn * BN;

    const int tx = tid & 15;
    const int ty = tid >> 4;

    float acc[4][4] = {{0.f}};

    for (int kc = 0; kc < K; kc += BK) {
#pragma unroll
        for (int i = 0; i < 8; i++) {
            int idx = tid + i * 256;
            int r = idx >> 5;
            int c = idx & 31;
            int col = kc + c;
            int trow = t0 + r;
            float av = (col < INDIM) ? x[(size_t)trow * INDIM + col]
                                     : ((col == INDIM) ? timev[trow] : 0.f);
            As[c][r] = av;
            int nrow = n0 + r;
            Bs[c][r] = (col < K) ? B[(size_t)nrow * K + col] : 0.f;
        }
        __syncthreads();

#pragma unroll
        for (int kk = 0; kk < BK; kk++) {
            float a[4], b[4];
#pragma unroll
            for (int i = 0; i < 4; i++) a[i] = As[kk][ty * 4 + i];
#pragma unroll
            for (int j = 0; j < 4; j++) b[j] = Bs[kk][tx * 4 + j];
#pragma unroll
            for (int i = 0; i < 4; i++)
#pragma unroll
                for (int j = 0; j < 4; j++)
                    acc[i][j] = fmaf(a[i], b[j], acc[i][j]);
        }
        __syncthreads();
    }

#pragma unroll
    for (int i = 0; i < 4; i++) {
        int trow = t0 + ty * 4 + i;
#pragma unroll
        for (int j = 0; j < 4; j++) {
            int n = n0 + tx * 4 + j;
            C[(size_t)trow * N + n] = acc[i][j] + bias1[n] + bias2[n];
        }
    }
}

// ---------------------------------------------------------------------------
// Fused dataflow 3-layer scan. No barriers, no flags: consumers poll the
// poisoned H rows directly. Occupancy pinned to 4 waves/EU so the register
// allocator has the full 128-VGPR budget; weights pinned resident via PIN2.
// ---------------------------------------------------------------------------
__global__ __launch_bounds__(1024)
__attribute__((amdgpu_waves_per_eu(4, 4)))
void fused_scan(
    const float* Whh1,
    const float* G1,
    const float* Wih2,
    const float* Whh2,
    const float* bih2,
    const float* bhh2,
    const float* h0_1, const float* c0_1,
    const float* h0_2, const float* c0_2,
    const float* h0_3, const float* c0_3,
    float* H1, float* H2, float* H3)
{
    __shared__ float hs1[HDIM];
    __shared__ float hs2[HDIM];
    __shared__ float hs3[HDIM];
    __shared__ float gbuf[16][4];  // L1: [unit 0..15][gate]; L23: 0-7 L2, 8-15 L3

    const int tid = threadIdx.x;
    const int wg  = blockIdx.x;
    const int q   = tid >> 6;      // wave 0..15
    const int s   = tid & 63;

    if (wg < NWG_L1) {
        // ------- Layer 1: WG owns 16 units, wave q owns unit u0+q -------
        const int u0 = wg << 4;
        const int u  = u0 + q;
        float2 w[4][8];
#pragma unroll
        for (int g = 0; g < 4; ++g) {
            const float* row = Whh1 + (size_t)((g << 10) + u) * HDIM + 2 * s;
#pragma unroll
            for (int m = 0; m < 8; ++m)
                w[g][m] = *(const float2*)(row + 128 * m);
        }
        float c1 = (tid < 16) ? c0_1[u0 + tid] : 0.f;

        for (int t = 0; t < TSTEPS; ++t) {
            // force weights live in VGPRs across the loop (zero instructions)
#pragma unroll
            for (int g = 0; g < 4; ++g)
#pragma unroll
                for (int m = 0; m < 8; ++m) PIN2(w[g][m]);

            float Gv0 = 0.f, Gv1 = 0.f, Gv2 = 0.f, Gv3 = 0.f;
            if (tid < 16) {   // prefetch gate inputs (normal cached loads)
                const float* gptr = G1 + (size_t)t * NGATE + u0 + tid;
                Gv0 = gptr[0];
                Gv1 = gptr[1024];
                Gv2 = gptr[2048];
                Gv3 = gptr[3072];
            }
            // stage h1[t-1]: poll the data itself
            hs1[tid] = (t == 0) ? h0_1[tid]
                               : poll_row(H1 + (size_t)(t - 1) * HDIM + tid);
            __syncthreads();                                   // A: staged

            float2 a0 = make_float2(0.f, 0.f), a1 = a0, a2 = a0, a3 = a0;
#pragma unroll
            for (int m = 0; m < 8; ++m) {
                float2 hv = *(const float2*)&hs1[2 * s + 128 * m];
                a0.x = fmaf(w[0][m].x, hv.x, a0.x);
                a0.y = fmaf(w[0][m].y, hv.y, a0.y);
                a1.x = fmaf(w[1][m].x, hv.x, a1.x);
                a1.y = fmaf(w[1][m].y, hv.y, a1.y);
                a2.x = fmaf(w[2][m].x, hv.x, a2.x);
                a2.y = fmaf(w[2][m].y, hv.y, a2.y);
                a3.x = fmaf(w[3][m].x, hv.x, a3.x);
                a3.y = fmaf(w[3][m].y, hv.y, a3.y);
            }
            float s0 = wave_sum64(a0.x + a0.y);
            float s1 = wave_sum64(a1.x + a1.y);
            float s2 = wave_sum64(a2.x + a2.y);
            float s3 = wave_sum64(a3.x + a3.y);
            if (s == 0) {
                gbuf[q][0] = s0;
                gbuf[q][1] = s1;
                gbuf[q][2] = s2;
                gbuf[q][3] = s3;
            }
            __syncthreads();                                   // B: sums ready

            if (tid < 16) {
                float gi = gbuf[tid][0] + Gv0;
                float gf = gbuf[tid][1] + Gv1;
                float gg = gbuf[tid][2] + Gv2;
                float go = gbuf[tid][3] + Gv3;
                float i_ = sigm(gi), f_ = sigm(gf), g_ = tanhf(gg), o_ = sigm(go);
                c1 = f_ * c1 + i_ * g_;
                float hn = o_ * tanhf(c1);
                agent_storef(H1 + (size_t)t * HDIM + u0 + tid, hn);
            }
            // no drain, no flag: the stored dwords ARE the signal
        }
    } else {
        // ---- Layers 2 & 3 (shared weights): WG owns 8 units ----
        const int ul = q >> 1;     // unit-local 0..7
        const int gp = q & 1;      // 0 -> gates (i,f), 1 -> gates (g,o)
        const int u0 = (wg - NWG_L1) << 3;
        const int u  = u0 + ul;
        float2 wi[2][8], wh[2][8];
#pragma unroll
        for (int j = 0; j < 2; ++j) {
            const float* ri = Wih2 + (size_t)(((2 * gp + j) << 10) + u) * HDIM + 2 * s;
            const float* rh = Whh2 + (size_t)(((2 * gp + j) << 10) + u) * HDIM + 2 * s;
#pragma unroll
            for (int m = 0; m < 8; ++m) {
                wi[j][m] = *(const float2*)(ri + 128 * m);
                wh[j][m] = *(const float2*)(rh + 128 * m);
            }
        }
        float bias0 = 0.f, bias1v = 0.f, bias2v = 0.f, bias3 = 0.f, cst = 0.f;
        if (tid < 16) {
            int uu = u0 + (tid & 7);
            bias0  = bih2[uu]        + bhh2[uu];
            bias1v = bih2[1024 + uu] + bhh2[1024 + uu];
            bias2v = bih2[2048 + uu] + bhh2[2048 + uu];
            bias3  = bih2[3072 + uu] + bhh2[3072 + uu];
            cst = (tid < 8) ? c0_2[u0 + tid] : c0_3[u0 + tid - 8];
        }

        // iteration t: layer2 tick t (needs h1[t], h2[t-1]) and
        //              layer3 tick t-1 (needs h2[t-1], h3[t-2])
        for (int t = 0; t <= TSTEPS; ++t) {
            // force weights live in VGPRs across the loop (zero instructions)
#pragma unroll
            for (int j = 0; j < 2; ++j)
#pragma unroll
                for (int m = 0; m < 8; ++m) { PIN2(wi[j][m]); PIN2(wh[j][m]); }

            const bool do2 = (t < TSTEPS);
            const bool do3 = (t >= 1);

            if (do2)
                hs1[tid] = poll_row(H1 + (size_t)t * HDIM + tid);
            hs2[tid] = (t == 0) ? h0_2[tid]
                                : poll_row(H2 + (size_t)(t - 1) * HDIM + tid);
            if (do3)
                hs3[tid] = (t == 1) ? h0_3[tid]
                                    : poll_row(H3 + (size_t)(t - 2) * HDIM + tid);
            __syncthreads();                                   // A: staged

            // unconditional dots; inactive-edge garbage discarded at update
            float2 p20 = make_float2(0.f, 0.f), p21 = p20, p30 = p20, p31 = p20;
#pragma unroll
            for (int m = 0; m < 8; ++m) {
                float2 h1v = *(const float2*)&hs1[2 * s + 128 * m];
                float2 h2v = *(const float2*)&hs2[2 * s + 128 * m];
                float2 h3v = *(const float2*)&hs3[2 * s + 128 * m];
                p20.x = fmaf(wi[0][m].x, h1v.x, p20.x);
                p20.y = fmaf(wi[0][m].y, h1v.y, p20.y);
                p21.x = fmaf(wi[1][m].x, h1v.x, p21.x);
                p21.y = fmaf(wi[1][m].y, h1v.y, p21.y);
                p20.x = fmaf(wh[0][m].x, h2v.x, p20.x);
                p20.y = fmaf(wh[0][m].y, h2v.y, p20.y);
                p21.x = fmaf(wh[1][m].x, h2v.x, p21.x);
                p21.y = fmaf(wh[1][m].y, h2v.y, p21.y);
                p30.x = fmaf(wi[0][m].x, h2v.x, p30.x);
                p30.y = fmaf(wi[0][m].y, h2v.y, p30.y);
                p31.x = fmaf(wi[1][m].x, h2v.x, p31.x);
                p31.y = fmaf(wi[1][m].y, h2v.y, p31.y);
                p30.x = fmaf(wh[0][m].x, h3v.x, p30.x);
                p30.y = fmaf(wh[0][m].y, h3v.y, p30.y);
                p31.x = fmaf(wh[1][m].x, h3v.x, p31.x);
                p31.y = fmaf(wh[1][m].y, h3v.y, p31.y);
            }
            float s20 = wave_sum64(p20.x + p20.y);
            float s21 = wave_sum64(p21.x + p21.y);
            float s30 = wave_sum64(p30.x + p30.y);
            float s31 = wave_sum64(p31.x + p31.y);
            if (s == 0) {
                gbuf[ul][2 * gp]          = s20;
                gbuf[ul][2 * gp + 1]      = s21;
                gbuf[8 + ul][2 * gp]      = s30;
                gbuf[8 + ul][2 * gp + 1]  = s31;
            }
            __syncthreads();                                   // B: sums ready

            if (tid < 16) {
                const bool act = (tid < 8) ? do2 : do3;
                if (act) {
                    float gi = gbuf[tid][0] + bias0;
                    float gf = gbuf[tid][1] + bias1v;
                    float gg = gbuf[tid][2] + bias2v;
                    float go = gbuf[tid][3] + bias3;
                    float i_ = sigm(gi), f_ = sigm(gf), g_ = tanhf(gg), o_ = sigm(go);
                    cst = f_ * cst + i_ * g_;
                    float hn = o_ * tanhf(cst);
                    float* dst = (tid < 8)
                        ? (H2 + (size_t)t * HDIM + u0 + tid)
                        : (H3 + (size_t)(t - 1) * HDIM + u0 + (tid - 8));
                    agent_storef(dst, hn);
                }
            }
        }
    }
}

// ---------------------------------------------------------------------------
// Attention
// ---------------------------------------------------------------------------
__global__ __launch_bounds__(256) void attn_dot(
    const float* __restrict__ H3, float* __restrict__ attn)
{
    const int t = blockIdx.x * 4 + (threadIdx.x >> 6);
    const int lane = threadIdx.x & 63;
    const float* hrow = H3 + (size_t)t * HDIM;
    const float* hf = H3 + (size_t)(TSTEPS - 1) * HDIM;
    float p = 0.f;
    for (int j = lane; j < HDIM; j += 64) p = fmaf(hrow[j], hf[j], p);
#pragma unroll
    for (int d = 32; d; d >>= 1) p += __shfl_down(p, d, 64);
    if (lane == 0) attn[t] = p;
}

__global__ __launch_bounds__(64) void softmax_1024(float* attn)
{
    const int lane = threadIdx.x;
    float vals[16];
    float m = -1e30f;
#pragma unroll
    for (int i = 0; i < 16; i++) {
        vals[i] = attn[lane + i * 64];
        m = fmaxf(m, vals[i]);
    }
#pragma unroll
    for (int d = 32; d; d >>= 1) m = fmaxf(m, __shfl_xor(m, d, 64));
    float s = 0.f;
#pragma unroll
    for (int i = 0; i < 16; i++) {
        vals[i] = expf(vals[i] - m);
        s += vals[i];
    }
#pragma unroll
    for (int d = 32; d; d >>= 1) s += __shfl_xor(s, d, 64);
    float inv = 1.f / s;
#pragma unroll
    for (int i = 0; i < 16; i++) attn[lane + i * 64] = vals[i] * inv;
}

__global__ __launch_bounds__(256) void context_kernel(
    const float* __restrict__ H3, const float* __restrict__ w,
    float* __restrict__ out)
{
    const int u = blockIdx.x * 4 + (threadIdx.x >> 6);
    const int lane = threadIdx.x & 63;
    float p = 0.f;
    for (int t = lane; t < TSTEPS; t += 64)
        p = fmaf(H3[(size_t)t * HDIM + u], w[t], p);
#pragma unroll
    for (int d = 32; d; d >>= 1) p += __shfl_down(p, d, 64);
    if (lane == 0) out[u] = p;
}

// ---------------------------------------------------------------------------
// Launch
// ---------------------------------------------------------------------------
extern "C" void kernel_launch(void* const* d_in, const int* in_sizes, int n_in,
                              void* d_out, int out_size, void* d_ws, size_t ws_size,
                              hipStream_t stream)
{
    const float* x     = (const float*)d_in[0];
    const float* timev = (const float*)d_in[1];
    const float* h0_1  = (const float*)d_in[2];
    const float* c0_1  = (const float*)d_in[3];
    const float* h0_2  = (const float*)d_in[4];
    const float* c0_2  = (const float*)d_in[5];
    const float* h0_3  = (const float*)d_in[6];
    const float* c0_3  = (const float*)d_in[7];
    const float* Wih1  = (const float*)d_in[8];
    const float* Whh1  = (const float*)d_in[9];
    const float* bih1  = (const float*)d_in[10];
    const float* bhh1  = (const float*)d_in[11];
    const float* Wih2  = (const float*)d_in[12];
    const float* Whh2  = (const float*)d_in[13];
    const float* bih2  = (const float*)d_in[14];
    const float* bhh2  = (const float*)d_in[15];

    float* ws   = (float*)d_ws;
    float* G    = ws;                          // 1024*4096
    float* H1   = G + (size_t)TSTEPS * NGATE;
    float* H2   = H1 + (size_t)TSTEPS * HDIM;
    float* H3   = H2 + (size_t)TSTEPS * HDIM;
    float* attn = H3 + (size_t)TSTEPS * HDIM;
    float* out  = (float*)d_out;

    // Poison H1..H3 (contiguous): the data-poll protocol depends on it.
    hipMemsetAsync(H1, 0xAA, (size_t)3 * TSTEPS * HDIM * sizeof(float), stream);

    // Layer-1 input gates: G = concat(x,time) @ Wih1^T + bih1 + bhh1
    gemm_tn<<<dim3(1024), dim3(256), 0, stream>>>(Wih1, bih1, bhh1, G,
                                                  TSTEPS, NGATE, INDIM + 1, x, timev);

    {
        const float* a0 = Whh1;  const float* a1 = G;
        const float* a2 = Wih2;  const float* a3 = Whh2;
        const float* a4 = bih2;  const float* a5 = bhh2;
        const float* a6 = h0_1;  const float* a7 = c0_1;
        const float* a8 = h0_2;  const float* a9 = c0_2;
        const float* a10 = h0_3; const float* a11 = c0_3;
        float* a12 = H1; float* a13 = H2; float* a14 = H3;
        void* args[] = {&a0,&a1,&a2,&a3,&a4,&a5,&a6,&a7,&a8,&a9,&a10,&a11,
                        &a12,&a13,&a14};
        hipLaunchCooperativeKernel((void*)fused_scan, dim3(NWG_TOT), dim3(1024),
                                   args, 0, stream);
    }

    // Attention
    attn_dot<<<dim3(256), dim3(256), 0, stream>>>(H3, attn);
    softmax_1024<<<dim3(1), dim3(64), 0, stream>>>(attn);
    context_kernel<<<dim3(256), dim3(256), 0, stream>>>(H3, attn, out);
}

// Round 11
// 4157.701 us; speedup vs baseline: 1.2770x; 1.2749x over previous
//
#include <hip/hip_runtime.h>

// Problem constants
#define TSTEPS 1024
#define HDIM   1024
#define INDIM  512
#define NGATE  4096     // 4*HDIM

// Fused-scan grid: 192 WGs x 1024 threads (proven-launchable coop envelope).
// L1 (wg<64): 16 units/WG, wave q owns unit u0+q, all 4 gates.
// L23: 8 units/WG, wave q owns unit u0+(q>>1), gate pair q&1, serving BOTH
//      layer 2 and layer 3 (shared weights).
#define NWG_L1  64
#define NWG_L23 128
#define NWG_TOT 192
#define POISON  0xAAAAAAAAu
#define SPIN_MAX (1 << 20)   // deadlock valve: fail loud, never hang

// ---------------------------------------------------------------------------
// R10 post-mortem: allocator pins VGPR budget at 64 regardless of
// waves_per_eu/launch_bounds/pins (r7-r10) -> 64 fp32 weights/thread can
// NEVER be resident -> ~48 MB/step L2/LLC refetch ≈ 3.5-4us/step floor.
// R11 fix: bf16-pack the weights (one-time prep kernel, RNE). Per-thread
// weight state becomes 32 uints (2 bf16 each) -> 32 VGPRs + ~25 working set
// fits the 64-VGPR budget, so residency is the natural allocation. Dot math
// stays fp32 (unpack = shift/and). Only weight STORAGE is rounded.
// ---------------------------------------------------------------------------
#define PINU(v) asm volatile("" : "+v"(v))

__device__ __forceinline__ float agent_loadf(const float* p) {
    return __hip_atomic_load(const_cast<float*>(p), __ATOMIC_RELAXED,
                             __HIP_MEMORY_SCOPE_AGENT);
}
__device__ __forceinline__ void agent_storef(float* p, float v) {
    __hip_atomic_store(p, v, __ATOMIC_RELAXED, __HIP_MEMORY_SCOPE_AGENT);
}
// Wave-cooperative poll: each lane owns one dword; loop until no lane's
// dword is the poison pattern. The poll IS the data load.
__device__ __forceinline__ float poll_row(const float* p) {
    float v = 0.f;
    for (int it = 0; it < SPIN_MAX; ++it) {
        v = agent_loadf(p);
        if (__ballot(__float_as_uint(v) == POISON) == 0ULL) break;
        __builtin_amdgcn_s_sleep(1);
    }
    return v;
}
__device__ __forceinline__ float wave_sum64(float v) {
#pragma unroll
    for (int d = 1; d < 64; d <<= 1) v += __shfl_xor(v, d, 64);
    return v;
}
__device__ __forceinline__ float sigm(float x) { return 1.f / (1.f + __expf(-x)); }

// unpack packed bf16 pair (lo = even col, hi = odd col) to fp32
__device__ __forceinline__ float bflo(unsigned u) {
    return __uint_as_float(u << 16);
}
__device__ __forceinline__ float bfhi(unsigned u) {
    return __uint_as_float(u & 0xffff0000u);
}

// ---------------------------------------------------------------------------
// Prep: pack fp32 matrix (rows x 1024) into bf16-pair uints (rows x 512),
// RNE rounding. dst[row*512 + j] = bf16(col 2j) | bf16(col 2j+1)<<16.
// ---------------------------------------------------------------------------
__global__ __launch_bounds__(256) void pack_bf16(
    const float* __restrict__ src, unsigned* __restrict__ dst, int n)
{
    int i = blockIdx.x * 256 + threadIdx.x;
    if (i < n) {
        unsigned ua = __float_as_uint(src[2 * i]);
        unsigned ub = __float_as_uint(src[2 * i + 1]);
        ua = (ua + 0x7fffu + ((ua >> 16) & 1u)) >> 16;
        ub = (ub + 0x7fffu + ((ub >> 16) & 1u)) >> 16;
        dst[i] = ua | (ub << 16);
    }
}

// ---------------------------------------------------------------------------
// GEMM for layer-1 input gates: G[t][n] = concat(x,time)[t] . Wih1[n] + b.
// (stays fp32 — one-shot, not the bottleneck)
// ---------------------------------------------------------------------------
#define BM 64
#define BN 64
#define BK 32

__global__ __launch_bounds__(256) void gemm_tn(
    const float* __restrict__ B,
    const float* __restrict__ bias1,
    const float* __restrict__ bias2,
    float* __restrict__ C,
    int M, int N, int K,
    const float* __restrict__ x,
    const float* __restrict__ timev)
{
    __shared__ float As[BK][BM + 4];
    __shared__ float Bs[BK][BN + 4];

    const int tid = threadIdx.x;
    const int mblocks = M / BM;
    const int bm = blockIdx.x % mblocks;
    const int bn = blockIdx.x / mblocks;
    const int t0 = bm * BM;
    const int n0 = bn * BN;

    const int tx = tid & 15;
    const int ty = tid >> 4;

    float acc[4][4] = {{0.f}};

    for (int kc = 0; kc < K; kc += BK) {
#pragma unroll
        for (int i = 0; i < 8; i++) {
            int idx = tid + i * 256;
            int r = idx >> 5;
            int c = idx & 31;
            int col = kc + c;
            int trow = t0 + r;
            float av = (col < INDIM) ? x[(size_t)trow * INDIM + col]
                                     : ((col == INDIM) ? timev[trow] : 0.f);
            As[c][r] = av;
            int nrow = n0 + r;
            Bs[c][r] = (col < K) ? B[(size_t)nrow * K + col] : 0.f;
        }
        __syncthreads();

#pragma unroll
        for (int kk = 0; kk < BK; kk++) {
            float a[4], b[4];
#pragma unroll
            for (int i = 0; i < 4; i++) a[i] = As[kk][ty * 4 + i];
#pragma unroll
            for (int j = 0; j < 4; j++) b[j] = Bs[kk][tx * 4 + j];
#pragma unroll
            for (int i = 0; i < 4; i++)
#pragma unroll
                for (int j = 0; j < 4; j++)
                    acc[i][j] = fmaf(a[i], b[j], acc[i][j]);
        }
        __syncthreads();
    }

#pragma unroll
    for (int i = 0; i < 4; i++) {
        int trow = t0 + ty * 4 + i;
#pragma unroll
        for (int j = 0; j < 4; j++) {
            int n = n0 + tx * 4 + j;
            C[(size_t)trow * N + n] = acc[i][j] + bias1[n] + bias2[n];
        }
    }
}

// ---------------------------------------------------------------------------
// Fused dataflow 3-layer scan. No barriers, no flags: consumers poll the
// poisoned H rows directly. Weights: bf16-packed, 32 uints/thread, resident.
// Wb* layout: row-major, 512 uints/row, uint j = cols (2j, 2j+1).
// Thread wants cols (2s+128m, 2s+128m+1) -> uint index s + 64m.
// ---------------------------------------------------------------------------
__global__ __launch_bounds__(1024, 4) void fused_scan(
    const unsigned* Wb1,      // packed Whh1, 4096 x 512
    const float* G1,
    const unsigned* Wbi2,     // packed Wih2, 4096 x 512
    const unsigned* Wbh2,     // packed Whh2, 4096 x 512
    const float* bih2,
    const float* bhh2,
    const float* h0_1, const float* c0_1,
    const float* h0_2, const float* c0_2,
    const float* h0_3, const float* c0_3,
    float* H1, float* H2, float* H3)
{
    __shared__ float hs1[HDIM];
    __shared__ float hs2[HDIM];
    __shared__ float hs3[HDIM];
    __shared__ float gbuf[16][4];  // L1: [unit 0..15][gate]; L23: 0-7 L2, 8-15 L3

    const int tid = threadIdx.x;
    const int wg  = blockIdx.x;
    const int q   = tid >> 6;      // wave 0..15
    const int s   = tid & 63;

    if (wg < NWG_L1) {
        // ------- Layer 1: WG owns 16 units, wave q owns unit u0+q -------
        const int u0 = wg << 4;
        const int u  = u0 + q;
        unsigned w[4][8];
#pragma unroll
        for (int g = 0; g < 4; ++g) {
            const unsigned* row = Wb1 + (size_t)((g << 10) + u) * 512 + s;
#pragma unroll
            for (int m = 0; m < 8; ++m)
                w[g][m] = row[64 * m];
        }
        float c1 = (tid < 16) ? c0_1[u0 + tid] : 0.f;

        for (int t = 0; t < TSTEPS; ++t) {
            // keep the 32 packed weights live in VGPRs (zero instructions)
#pragma unroll
            for (int g = 0; g < 4; ++g)
#pragma unroll
                for (int m = 0; m < 8; ++m) PINU(w[g][m]);

            float Gv0 = 0.f, Gv1 = 0.f, Gv2 = 0.f, Gv3 = 0.f;
            if (tid < 16) {   // prefetch gate inputs (normal cached loads)
                const float* gptr = G1 + (size_t)t * NGATE + u0 + tid;
                Gv0 = gptr[0];
                Gv1 = gptr[1024];
                Gv2 = gptr[2048];
                Gv3 = gptr[3072];
            }
            // stage h1[t-1]: poll the data itself
            hs1[tid] = (t == 0) ? h0_1[tid]
                               : poll_row(H1 + (size_t)(t - 1) * HDIM + tid);
            __syncthreads();                                   // A: staged

            float2 a0 = make_float2(0.f, 0.f), a1 = a0, a2 = a0, a3 = a0;
#pragma unroll
            for (int m = 0; m < 8; ++m) {
                float2 hv = *(const float2*)&hs1[2 * s + 128 * m];
                a0.x = fmaf(bflo(w[0][m]), hv.x, a0.x);
                a0.y = fmaf(bfhi(w[0][m]), hv.y, a0.y);
                a1.x = fmaf(bflo(w[1][m]), hv.x, a1.x);
                a1.y = fmaf(bfhi(w[1][m]), hv.y, a1.y);
                a2.x = fmaf(bflo(w[2][m]), hv.x, a2.x);
                a2.y = fmaf(bfhi(w[2][m]), hv.y, a2.y);
                a3.x = fmaf(bflo(w[3][m]), hv.x, a3.x);
                a3.y = fmaf(bfhi(w[3][m]), hv.y, a3.y);
            }
            float s0 = wave_sum64(a0.x + a0.y);
            float s1 = wave_sum64(a1.x + a1.y);
            float s2 = wave_sum64(a2.x + a2.y);
            float s3 = wave_sum64(a3.x + a3.y);
            if (s == 0) {
                gbuf[q][0] = s0;
                gbuf[q][1] = s1;
                gbuf[q][2] = s2;
                gbuf[q][3] = s3;
            }
            __syncthreads();                                   // B: sums ready

            if (tid < 16) {
                float gi = gbuf[tid][0] + Gv0;
                float gf = gbuf[tid][1] + Gv1;
                float gg = gbuf[tid][2] + Gv2;
                float go = gbuf[tid][3] + Gv3;
                float i_ = sigm(gi), f_ = sigm(gf), g_ = tanhf(gg), o_ = sigm(go);
                c1 = f_ * c1 + i_ * g_;
                float hn = o_ * tanhf(c1);
                agent_storef(H1 + (size_t)t * HDIM + u0 + tid, hn);
            }
            // no drain, no flag: the stored dwords ARE the signal
        }
    } else {
        // ---- Layers 2 & 3 (shared weights): WG owns 8 units ----
        const int ul = q >> 1;     // unit-local 0..7
        const int gp = q & 1;      // 0 -> gates (i,f), 1 -> gates (g,o)
        const int u0 = (wg - NWG_L1) << 3;
        const int u  = u0 + ul;
        unsigned wi[2][8], wh[2][8];
#pragma unroll
        for (int j = 0; j < 2; ++j) {
            const unsigned* ri = Wbi2 + (size_t)(((2 * gp + j) << 10) + u) * 512 + s;
            const unsigned* rh = Wbh2 + (size_t)(((2 * gp + j) << 10) + u) * 512 + s;
#pragma unroll
            for (int m = 0; m < 8; ++m) {
                wi[j][m] = ri[64 * m];
                wh[j][m] = rh[64 * m];
            }
        }
        float bias0 = 0.f, bias1v = 0.f, bias2v = 0.f, bias3 = 0.f, cst = 0.f;
        if (tid < 16) {
            int uu = u0 + (tid & 7);
            bias0  = bih2[uu]        + bhh2[uu];
            bias1v = bih2[1024 + uu] + bhh2[1024 + uu];
            bias2v = bih2[2048 + uu] + bhh2[2048 + uu];
            bias3  = bih2[3072 + uu] + bhh2[3072 + uu];
            cst = (tid < 8) ? c0_2[u0 + tid] : c0_3[u0 + tid - 8];
        }

        // iteration t: layer2 tick t (needs h1[t], h2[t-1]) and
        //              layer3 tick t-1 (needs h2[t-1], h3[t-2])
        for (int t = 0; t <= TSTEPS; ++t) {
            // keep the 32 packed weights live in VGPRs (zero instructions)
#pragma unroll
            for (int j = 0; j < 2; ++j)
#pragma unroll
                for (int m = 0; m < 8; ++m) { PINU(wi[j][m]); PINU(wh[j][m]); }

            const bool do2 = (t < TSTEPS);
            const bool do3 = (t >= 1);

            if (do2)
                hs1[tid] = poll_row(H1 + (size_t)t * HDIM + tid);
            hs2[tid] = (t == 0) ? h0_2[tid]
                                : poll_row(H2 + (size_t)(t - 1) * HDIM + tid);
            if (do3)
                hs3[tid] = (t == 1) ? h0_3[tid]
                                    : poll_row(H3 + (size_t)(t - 2) * HDIM + tid);
            __syncthreads();                                   // A: staged

            // unconditional dots; inactive-edge garbage discarded at update.
            // wi unpacks are shared between the L2 (h1) and L3 (h2) dots.
            float2 p20 = make_float2(0.f, 0.f), p21 = p20, p30 = p20, p31 = p20;
#pragma unroll
            for (int m = 0; m < 8; ++m) {
                float2 h1v = *(const float2*)&hs1[2 * s + 128 * m];
                float2 h2v = *(const float2*)&hs2[2 * s + 128 * m];
                float2 h3v = *(const float2*)&hs3[2 * s + 128 * m];
                float wi0l = bflo(wi[0][m]), wi0h = bfhi(wi[0][m]);
                float wi1l = bflo(wi[1][m]), wi1h = bfhi(wi[1][m]);
                float wh0l = bflo(wh[0][m]), wh0h = bfhi(wh[0][m]);
                float wh1l = bflo(wh[1][m]), wh1h = bfhi(wh[1][m]);
                p20.x = fmaf(wi0l, h1v.x, p20.x);
                p20.y = fmaf(wi0h, h1v.y, p20.y);
                p21.x = fmaf(wi1l, h1v.x, p21.x);
                p21.y = fmaf(wi1h, h1v.y, p21.y);
                p20.x = fmaf(wh0l, h2v.x, p20.x);
                p20.y = fmaf(wh0h, h2v.y, p20.y);
                p21.x = fmaf(wh1l, h2v.x, p21.x);
                p21.y = fmaf(wh1h, h2v.y, p21.y);
                p30.x = fmaf(wi0l, h2v.x, p30.x);
                p30.y = fmaf(wi0h, h2v.y, p30.y);
                p31.x = fmaf(wi1l, h2v.x, p31.x);
                p31.y = fmaf(wi1h, h2v.y, p31.y);
                p30.x = fmaf(wh0l, h3v.x, p30.x);
                p30.y = fmaf(wh0h, h3v.y, p30.y);
                p31.x = fmaf(wh1l, h3v.x, p31.x);
                p31.y = fmaf(wh1h, h3v.y, p31.y);
            }
            float s20 = wave_sum64(p20.x + p20.y);
            float s21 = wave_sum64(p21.x + p21.y);
            float s30 = wave_sum64(p30.x + p30.y);
            float s31 = wave_sum64(p31.x + p31.y);
            if (s == 0) {
                gbuf[ul][2 * gp]          = s20;
                gbuf[ul][2 * gp + 1]      = s21;
                gbuf[8 + ul][2 * gp]      = s30;
                gbuf[8 + ul][2 * gp + 1]  = s31;
            }
            __syncthreads();                                   // B: sums ready

            if (tid < 16) {
                const bool act = (tid < 8) ? do2 : do3;
                if (act) {
                    float gi = gbuf[tid][0] + bias0;
                    float gf = gbuf[tid][1] + bias1v;
                    float gg = gbuf[tid][2] + bias2v;
                    float go = gbuf[tid][3] + bias3;
                    float i_ = sigm(gi), f_ = sigm(gf), g_ = tanhf(gg), o_ = sigm(go);
                    cst = f_ * cst + i_ * g_;
                    float hn = o_ * tanhf(cst);
                    float* dst = (tid < 8)
                        ? (H2 + (size_t)t * HDIM + u0 + tid)
                        : (H3 + (size_t)(t - 1) * HDIM + u0 + (tid - 8));
                    agent_storef(dst, hn);
                }
            }
        }
    }
}

// ---------------------------------------------------------------------------
// Attention
// ---------------------------------------------------------------------------
__global__ __launch_bounds__(256) void attn_dot(
    const float* __restrict__ H3, float* __restrict__ attn)
{
    const int t = blockIdx.x * 4 + (threadIdx.x >> 6);
    const int lane = threadIdx.x & 63;
    const float* hrow = H3 + (size_t)t * HDIM;
    const float* hf = H3 + (size_t)(TSTEPS - 1) * HDIM;
    float p = 0.f;
    for (int j = lane; j < HDIM; j += 64) p = fmaf(hrow[j], hf[j], p);
#pragma unroll
    for (int d = 32; d; d >>= 1) p += __shfl_down(p, d, 64);
    if (lane == 0) attn[t] = p;
}

__global__ __launch_bounds__(64) void softmax_1024(float* attn)
{
    const int lane = threadIdx.x;
    float vals[16];
    float m = -1e30f;
#pragma unroll
    for (int i = 0; i < 16; i++) {
        vals[i] = attn[lane + i * 64];
        m = fmaxf(m, vals[i]);
    }
#pragma unroll
    for (int d = 32; d; d >>= 1) m = fmaxf(m, __shfl_xor(m, d, 64));
    float s = 0.f;
#pragma unroll
    for (int i = 0; i < 16; i++) {
        vals[i] = expf(vals[i] - m);
        s += vals[i];
    }
#pragma unroll
    for (int d = 32; d; d >>= 1) s += __shfl_xor(s, d, 64);
    float inv = 1.f / s;
#pragma unroll
    for (int i = 0; i < 16; i++) attn[lane + i * 64] = vals[i] * inv;
}

__global__ __launch_bounds__(256) void context_kernel(
    const float* __restrict__ H3, const float* __restrict__ w,
    float* __restrict__ out)
{
    const int u = blockIdx.x * 4 + (threadIdx.x >> 6);
    const int lane = threadIdx.x & 63;
    float p = 0.f;
    for (int t = lane; t < TSTEPS; t += 64)
        p = fmaf(H3[(size_t)t * HDIM + u], w[t], p);
#pragma unroll
    for (int d = 32; d; d >>= 1) p += __shfl_down(p, d, 64);
    if (lane == 0) out[u] = p;
}

// ---------------------------------------------------------------------------
// Launch
// ---------------------------------------------------------------------------
extern "C" void kernel_launch(void* const* d_in, const int* in_sizes, int n_in,
                              void* d_out, int out_size, void* d_ws, size_t ws_size,
                              hipStream_t stream)
{
    const float* x     = (const float*)d_in[0];
    const float* timev = (const float*)d_in[1];
    const float* h0_1  = (const float*)d_in[2];
    const float* c0_1  = (const float*)d_in[3];
    const float* h0_2  = (const float*)d_in[4];
    const float* c0_2  = (const float*)d_in[5];
    const float* h0_3  = (const float*)d_in[6];
    const float* c0_3  = (const float*)d_in[7];
    const float* Wih1  = (const float*)d_in[8];
    const float* Whh1  = (const float*)d_in[9];
    const float* bih1  = (const float*)d_in[10];
    const float* bhh1  = (const float*)d_in[11];
    const float* Wih2  = (const float*)d_in[12];
    const float* Whh2  = (const float*)d_in[13];
    const float* bih2  = (const float*)d_in[14];
    const float* bhh2  = (const float*)d_in[15];

    float* ws   = (float*)d_ws;
    float* G    = ws;                          // 1024*4096 fp32
    float* H1   = G + (size_t)TSTEPS * NGATE;
    float* H2   = H1 + (size_t)TSTEPS * HDIM;
    float* H3   = H2 + (size_t)TSTEPS * HDIM;
    float* attn = H3 + (size_t)TSTEPS * HDIM;
    unsigned* Wb1  = (unsigned*)(attn + TSTEPS);          // 4096*512 uints
    unsigned* Wbi2 = Wb1 + (size_t)NGATE * 512;
    unsigned* Wbh2 = Wbi2 + (size_t)NGATE * 512;
    float* out  = (float*)d_out;

    // Poison H1..H3 (contiguous): the data-poll protocol depends on it.
    hipMemsetAsync(H1, 0xAA, (size_t)3 * TSTEPS * HDIM * sizeof(float), stream);

    // Pack the three scan weight matrices to bf16 pairs (one-time, ~15us).
    {
        const int n = NGATE * 512;            // uints per matrix
        pack_bf16<<<dim3(n / 256), dim3(256), 0, stream>>>(Whh1, Wb1, n);
        pack_bf16<<<dim3(n / 256), dim3(256), 0, stream>>>(Wih2, Wbi2, n);
        pack_bf16<<<dim3(n / 256), dim3(256), 0, stream>>>(Whh2, Wbh2, n);
    }

    // Layer-1 input gates: G = concat(x,time) @ Wih1^T + bih1 + bhh1 (fp32)
    gemm_tn<<<dim3(1024), dim3(256), 0, stream>>>(Wih1, bih1, bhh1, G,
                                                  TSTEPS, NGATE, INDIM + 1, x, timev);

    {
        const unsigned* a0 = Wb1;  const float* a1 = G;
        const unsigned* a2 = Wbi2; const unsigned* a3 = Wbh2;
        const float* a4 = bih2;  const float* a5 = bhh2;
        const float* a6 = h0_1;  const float* a7 = c0_1;
        const float* a8 = h0_2;  const float* a9 = c0_2;
        const float* a10 = h0_3; const float* a11 = c0_3;
        float* a12 = H1; float* a13 = H2; float* a14 = H3;
        void* args[] = {&a0,&a1,&a2,&a3,&a4,&a5,&a6,&a7,&a8,&a9,&a10,&a11,
                        &a12,&a13,&a14};
        hipLaunchCooperativeKernel((void*)fused_scan, dim3(NWG_TOT), dim3(1024),
                                   args, 0, stream);
    }

    // Attention
    attn_dot<<<dim3(256), dim3(256), 0, stream>>>(H3, attn);
    softmax_1024<<<dim3(1), dim3(64), 0, stream>>>(attn);
    context_kernel<<<dim3(256), dim3(256), 0, stream>>>(H3, attn, out);
}